// Round 2
// baseline (1172.024 us; speedup 1.0000x reference)
//
#include <hip/hip_runtime.h>
#include <hip/hip_fp16.h>
#include <cstdint>
#include <cstddef>

// Problem dims (fixed by the reference)
#define TT 1024
#define BB 64
#define DD 512
#define HH 1024
#define MM (TT * BB)   // 65536 rows for the batched GEMM

typedef _Float16 f16;
typedef _Float16 f16x8 __attribute__((ext_vector_type(8)));
typedef float f32x4 __attribute__((ext_vector_type(4)));

// ---------------------------------------------------------------- converts
__global__ void cvt_f32_to_f16(const float* __restrict__ src,
                               f16* __restrict__ dst, int n) {
    int i = blockIdx.x * blockDim.x + threadIdx.x;
    int idx = i * 8;
    if (idx + 8 <= n) {
        float4 a = *reinterpret_cast<const float4*>(src + idx);
        float4 b = *reinterpret_cast<const float4*>(src + idx + 4);
        f16x8 o;
        o[0] = (f16)a.x; o[1] = (f16)a.y; o[2] = (f16)a.z; o[3] = (f16)a.w;
        o[4] = (f16)b.x; o[5] = (f16)b.y; o[6] = (f16)b.z; o[7] = (f16)b.w;
        *reinterpret_cast<f16x8*>(dst + idx) = o;
    } else {
        for (int k = idx; k < n; ++k) dst[k] = (f16)src[k];
    }
}

// ---------------------------------------------------------------- GEMM
// C[M,N] = A[M,K] (f16 row-major) * W[N,K]^T (f16 row-major) + bias[N]
// 256x256 tile, BK=32, 8 waves (2M x 4N), 4-deep LDS ring per matrix,
// counted vmcnt(8) gate once per K-tile (never drained to 0 mid-loop),
// LDS XOR swizzle (row&3)<<4 within 64-B rows, setprio around MFMA.
__device__ __forceinline__ void gload16(const void* g, void* l) {
    __builtin_amdgcn_global_load_lds(
        (const __attribute__((address_space(1))) void*)g,
        (__attribute__((address_space(3))) void*)l, 16, 0, 0);
}

// Stage one 256x32 f16 K-tile (16 KiB) with 512 threads x 2 x 16B loads.
// LDS dest stays lane-linear (gload_lds requirement); the swizzle is applied
// by inverse-permuting the GLOBAL source address (m173 pattern).
__device__ __forceinline__ void stage_tile(const f16* __restrict__ G,
                                           int rowbase, int K, int ktile,
                                           f16* lbuf, int tid) {
    #pragma unroll
    for (int j = 0; j < 2; ++j) {
        int p = (j * 512 + tid) * 16;            // physical LDS byte offset
        int L = p ^ (((p >> 6) & 3) << 4);       // logical byte offset
        int row  = L >> 6;                       // 0..255
        int colB = L & 63;                       // byte within 64-B row
        const f16* g = G + (size_t)(rowbase + row) * K + ktile * 32 + (colB >> 1);
        gload16(g, (char*)lbuf + p);
    }
}

template <typename TC>
__global__ __launch_bounds__(512, 2) void gemm2(
    const f16* __restrict__ A, const f16* __restrict__ W,
    const float* __restrict__ bias, TC* __restrict__ C,
    int M, int N, int K) {
    __shared__ f16 Abuf[4][256 * 32];   // 64 KiB ring (4 K-tiles)
    __shared__ f16 Bbuf[4][256 * 32];   // 64 KiB ring

    const int tid  = threadIdx.x;
    const int lane = tid & 63;
    const int wid  = tid >> 6;      // 0..7
    const int wm   = wid >> 2;      // 0..1 -> 128-row strip
    const int wn   = wid & 3;       // 0..3 -> 64-col strip
    const int lr   = lane & 15;
    const int cswz = ((lane >> 4) << 4) ^ ((lr & 3) << 4);  // swizzled col byte

    // XCD-bijective block swizzle, col-fastest (A-panel L2 reuse per XCD)
    const int nwg = gridDim.x;
    int bid = blockIdx.x;
    int wg  = (nwg % 8 == 0) ? ((bid & 7) * (nwg >> 3) + (bid >> 3)) : bid;
    const int ncol = N >> 8;                 // N/256 col-blocks
    const int brow = (wg / ncol) << 8;
    const int bcol = (wg % ncol) << 8;

    const int NT = K >> 5;                   // K-tiles of 32

    f32x4 acc[8][4] = {};

    // Prologue: stage tiles 0..2, gate so tile 0 is complete (12 issued, 8 allowed)
    for (int u = 0; u < 3; ++u) {
        stage_tile(A, brow, K, u, Abuf[u], tid);
        stage_tile(W, bcol, K, u, Bbuf[u], tid);
    }
    asm volatile("s_waitcnt vmcnt(8)" ::: "memory");
    __builtin_amdgcn_s_barrier();

    for (int t = 0; t < NT; ++t) {
        const f16* As = Abuf[t & 3];
        const f16* Bs = Bbuf[t & 3];
        // ---- phase 0: B frags + A frags (rows 0..63 of wave strip)
        f16x8 bf[4], af[4];
        #pragma unroll
        for (int fn = 0; fn < 4; ++fn) {
            int r = wn * 64 + fn * 16 + lr;
            bf[fn] = *reinterpret_cast<const f16x8*>((const char*)Bs + r * 64 + cswz);
        }
        #pragma unroll
        for (int i = 0; i < 4; ++i) {
            int r = wm * 128 + i * 16 + lr;
            af[i] = *reinterpret_cast<const f16x8*>((const char*)As + r * 64 + cswz);
        }
        if (t + 3 < NT) stage_tile(A, brow, K, t + 3, Abuf[(t + 3) & 3], tid);
        __builtin_amdgcn_s_barrier();
        __builtin_amdgcn_s_setprio(1);
        #pragma unroll
        for (int i = 0; i < 4; ++i)
            #pragma unroll
            for (int fn = 0; fn < 4; ++fn)
                acc[i][fn] = __builtin_amdgcn_mfma_f32_16x16x32_f16(
                    af[i], bf[fn], acc[i][fn], 0, 0, 0);
        __builtin_amdgcn_s_setprio(0);
        __builtin_amdgcn_s_barrier();

        // ---- phase 1: A frags (rows 64..127 of wave strip)
        #pragma unroll
        for (int i = 0; i < 4; ++i) {
            int r = wm * 128 + (4 + i) * 16 + lr;
            af[i] = *reinterpret_cast<const f16x8*>((const char*)As + r * 64 + cswz);
        }
        if (t + 3 < NT) stage_tile(W, bcol, K, t + 3, Bbuf[(t + 3) & 3], tid);
        __builtin_amdgcn_s_barrier();
        __builtin_amdgcn_s_setprio(1);
        #pragma unroll
        for (int i = 0; i < 4; ++i)
            #pragma unroll
            for (int fn = 0; fn < 4; ++fn)
                acc[4 + i][fn] = __builtin_amdgcn_mfma_f32_16x16x32_f16(
                    af[i], bf[fn], acc[4 + i][fn], 0, 0, 0);
        __builtin_amdgcn_s_setprio(0);
        // counted gate: allow the (up to) 8 loads of tiles t+2/t+3 to stay in
        // flight; forces tile t+1 complete. Tail tiles tighten the count.
        if (t + 3 < NT)      { asm volatile("s_waitcnt vmcnt(8)" ::: "memory"); }
        else if (t + 2 < NT) { asm volatile("s_waitcnt vmcnt(4)" ::: "memory"); }
        else                 { asm volatile("s_waitcnt vmcnt(0)" ::: "memory"); }
        __builtin_amdgcn_s_barrier();
    }

    // Epilogue: bias + store. C/D frag layout: col = lane&15, row = (lane>>4)*4+j
    #pragma unroll
    for (int fn = 0; fn < 4; ++fn) {
        int col = bcol + wn * 64 + fn * 16 + lr;
        float bv = bias[col];
        #pragma unroll
        for (int fm = 0; fm < 8; ++fm) {
            int row0 = brow + wm * 128 + fm * 16 + (lane >> 4) * 4;
            #pragma unroll
            for (int j = 0; j < 4; ++j) {
                C[(size_t)(row0 + j) * N + col] = (TC)(acc[fm][fn][j] + bv);
            }
        }
    }
}

// ---------------------------------------------------------------- scan
// h_t = tanh(pre_t + h_{t-1} * w), one thread per (b,h) element.
// PF-deep load pipeline hides HBM latency under the serial tanh chain.
// In-place f32 variant is safe: thread idx only touches column idx, and
// reads run PF steps ahead of writes.
template <typename TI, typename TO>
__global__ void scan_kernel(const TI* __restrict__ pre,
                            const float* __restrict__ w, TO* out) {
    const int S = BB * HH;  // 65536
    int idx = blockIdx.x * blockDim.x + threadIdx.x;
    if (idx >= S) return;
    float wv = w[idx & (HH - 1)];

    constexpr int PF = 32;
    float buf[PF];
    #pragma unroll
    for (int i = 0; i < PF; ++i) buf[i] = (float)pre[(size_t)i * S + idx];

    float h = 0.f;
    for (int t0 = 0; t0 < TT; t0 += PF) {
        #pragma unroll
        for (int i = 0; i < PF; ++i) {
            int tp = t0 + i + PF;
            float nv = (tp < TT) ? (float)pre[(size_t)tp * S + idx] : 0.f;
            h = tanhf(fmaf(h, wv, buf[i]));
            out[(size_t)(t0 + i) * S + idx] = (TO)h;
            buf[i] = nv;
        }
    }
}

__global__ void zero_kernel(float* p, int n) {
    int i = blockIdx.x * blockDim.x + threadIdx.x;
    if (i < n) p[i] = 0.f;
}

// ---------------------------------------------------------------- launch
extern "C" void kernel_launch(void* const* d_in, const int* in_sizes, int n_in,
                              void* d_out, int out_size, void* d_ws, size_t ws_size,
                              hipStream_t stream) {
    const float* x  = (const float*)d_in[0];  // [T,B,D]
    const float* W0 = (const float*)d_in[1];  // [H,D]
    const float* w0 = (const float*)d_in[2];  // [H]
    const float* b0 = (const float*)d_in[3];  // [H]
    const float* W1 = (const float*)d_in[4];  // [H,H]
    const float* w1 = (const float*)d_in[5];  // [H]
    const float* b1 = (const float*)d_in[6];  // [H]
    float* out = (float*)d_out;

    // ws layout:
    //   [0, M*H*2)          : big f16 region (x_f16 first, then out0_f16)
    //   [M*H*2, +H*D*2)     : W0 f16
    //   [.., +H*H*2)        : W1 f16
    //   [.., +M*H*2)        : pre1 f16 (only if ws is big enough)
    const size_t SZ_big = (size_t)MM * HH * sizeof(f16);      // 134 MB
    const size_t O_W0   = SZ_big;
    const size_t O_W1   = O_W0 + (size_t)HH * DD * sizeof(f16);
    const size_t O_pre1 = O_W1 + (size_t)HH * HH * sizeof(f16);
    const bool f16pre1  = (ws_size >= O_pre1 + SZ_big);

    f16* big   = (f16*)d_ws;
    f16* W0h   = (f16*)((char*)d_ws + O_W0);
    f16* W1h   = (f16*)((char*)d_ws + O_W1);
    f16* pre1h = (f16*)((char*)d_ws + O_pre1);

    const int nwg = (MM / 256) * (HH / 256);   // 1024 blocks

    // 1) convert x and weights to f16
    cvt_f32_to_f16<<<(MM * DD) / 8 / 256, 256, 0, stream>>>(x, big, MM * DD);
    cvt_f32_to_f16<<<(HH * DD) / 8 / 256, 256, 0, stream>>>(W0, W0h, HH * DD);
    cvt_f32_to_f16<<<(HH * HH) / 8 / 256, 256, 0, stream>>>(W1, W1h, HH * HH);

    // 2) pre0 = x_f16 @ W0^T + b0 -> d_out reused as f16 scratch
    gemm2<f16><<<nwg, 512, 0, stream>>>(big, W0h, b0, (f16*)d_out, MM, HH, DD);

    // 3) scan layer 0: pre0(f16, d_out) -> out0(f16) into ws big region
    scan_kernel<f16, f16><<<(BB * HH) / 256, 256, 0, stream>>>(
        (const f16*)d_out, w0, big);

    if (f16pre1) {
        // 4) pre1 = out0 @ W1^T + b1 (f16) -> ws
        gemm2<f16><<<nwg, 512, 0, stream>>>(big, W1h, b1, pre1h, MM, HH, HH);
        // 5) scan layer 1: pre1(f16, ws) -> out (f32)
        scan_kernel<f16, float><<<(BB * HH) / 256, 256, 0, stream>>>(
            pre1h, w1, out);
    } else {
        // 4) pre1 (f32) -> d_out, then in-place scan
        gemm2<float><<<nwg, 512, 0, stream>>>(big, W1h, b1, out, MM, HH, HH);
        scan_kernel<float, float><<<(BB * HH) / 256, 256, 0, stream>>>(
            out, w1, out);
    }

    // 6) hidden output: zeros [2,B,H] appended after [T,B,H]
    zero_kernel<<<(2 * BB * HH) / 256, 256, 0, stream>>>(
        out + (size_t)MM * HH, 2 * BB * HH);
}

// Round 4
// 499.583 us; speedup vs baseline: 2.3460x; 2.3460x over previous
//
#include <hip/hip_runtime.h>
#include <hip/hip_fp16.h>
#include <cstdint>
#include <cstddef>

// Problem dims (fixed by the reference)
#define TT 1024
#define BB 64
#define DD 512
#define HH 1024
#define MM (TT * BB)   // 65536 rows for the batched GEMM

typedef _Float16 f16;
typedef _Float16 f16x8 __attribute__((ext_vector_type(8)));
typedef float f32x4 __attribute__((ext_vector_type(4)));

// ---------------------------------------------------------------- converts
__global__ void cvt_f32_to_f16(const float* __restrict__ src,
                               f16* __restrict__ dst, int n) {
    int i = blockIdx.x * blockDim.x + threadIdx.x;
    int idx = i * 8;
    if (idx + 8 <= n) {
        float4 a = *reinterpret_cast<const float4*>(src + idx);
        float4 b = *reinterpret_cast<const float4*>(src + idx + 4);
        f16x8 o;
        o[0] = (f16)a.x; o[1] = (f16)a.y; o[2] = (f16)a.z; o[3] = (f16)a.w;
        o[4] = (f16)b.x; o[5] = (f16)b.y; o[6] = (f16)b.z; o[7] = (f16)b.w;
        *reinterpret_cast<f16x8*>(dst + idx) = o;
    } else {
        for (int k = idx; k < n; ++k) dst[k] = (f16)src[k];
    }
}

// ---------------------------------------------------------------- GEMM
// C[M,N] = A[M,K] (f16 row-major) * W[N,K]^T (f16 row-major) + bias[N]
// 256x256 tile, BK=32, 8 waves (2M x 4N), 4-deep LDS ring per matrix,
// counted vmcnt(8) gate once per K-tile (never drained to 0 mid-loop),
// LDS XOR swizzle (row&3)<<4 within 64-B rows, setprio around MFMA.
__device__ __forceinline__ void gload16(const void* g, void* l) {
    __builtin_amdgcn_global_load_lds(
        (const __attribute__((address_space(1))) void*)g,
        (__attribute__((address_space(3))) void*)l, 16, 0, 0);
}

// Stage one 256x32 f16 K-tile (16 KiB) with 512 threads x 2 x 16B loads.
// LDS dest stays lane-linear (gload_lds requirement); the swizzle is applied
// by inverse-permuting the GLOBAL source address (m173 pattern).
__device__ __forceinline__ void stage_tile(const f16* __restrict__ G,
                                           int rowbase, int K, int ktile,
                                           f16* lbuf, int tid) {
    #pragma unroll
    for (int j = 0; j < 2; ++j) {
        int p = (j * 512 + tid) * 16;            // physical LDS byte offset
        int L = p ^ (((p >> 6) & 3) << 4);       // logical byte offset
        int row  = L >> 6;                       // 0..255
        int colB = L & 63;                       // byte within 64-B row
        const f16* g = G + (size_t)(rowbase + row) * K + ktile * 32 + (colB >> 1);
        gload16(g, (char*)lbuf + p);
    }
}

template <typename TC>
__global__ __launch_bounds__(512, 2) void gemm2(
    const f16* __restrict__ A, const f16* __restrict__ W,
    const float* __restrict__ bias, TC* __restrict__ C,
    int M, int N, int K) {
    __shared__ f16 Abuf[4][256 * 32];   // 64 KiB ring (4 K-tiles)
    __shared__ f16 Bbuf[4][256 * 32];   // 64 KiB ring

    const int tid  = threadIdx.x;
    const int lane = tid & 63;
    const int wid  = tid >> 6;      // 0..7
    const int wm   = wid >> 2;      // 0..1 -> 128-row strip
    const int wn   = wid & 3;       // 0..3 -> 64-col strip
    const int lr   = lane & 15;
    const int cswz = ((lane >> 4) << 4) ^ ((lr & 3) << 4);  // swizzled col byte

    // XCD-bijective block swizzle, col-fastest (A-panel L2 reuse per XCD)
    const int nwg = gridDim.x;
    int bid = blockIdx.x;
    int wg  = (nwg % 8 == 0) ? ((bid & 7) * (nwg >> 3) + (bid >> 3)) : bid;
    const int ncol = N >> 8;                 // N/256 col-blocks
    const int brow = (wg / ncol) << 8;
    const int bcol = (wg % ncol) << 8;

    const int NT = K >> 5;                   // K-tiles of 32

    f32x4 acc[8][4] = {};

    // Prologue: stage tiles 0..2, gate so tile 0 is complete (12 issued, 8 allowed)
    for (int u = 0; u < 3; ++u) {
        stage_tile(A, brow, K, u, Abuf[u], tid);
        stage_tile(W, bcol, K, u, Bbuf[u], tid);
    }
    asm volatile("s_waitcnt vmcnt(8)" ::: "memory");
    __builtin_amdgcn_s_barrier();

    for (int t = 0; t < NT; ++t) {
        const f16* As = Abuf[t & 3];
        const f16* Bs = Bbuf[t & 3];
        // ---- phase 0: B frags + A frags (rows 0..63 of wave strip)
        f16x8 bf[4], af[4];
        #pragma unroll
        for (int fn = 0; fn < 4; ++fn) {
            int r = wn * 64 + fn * 16 + lr;
            bf[fn] = *reinterpret_cast<const f16x8*>((const char*)Bs + r * 64 + cswz);
        }
        #pragma unroll
        for (int i = 0; i < 4; ++i) {
            int r = wm * 128 + i * 16 + lr;
            af[i] = *reinterpret_cast<const f16x8*>((const char*)As + r * 64 + cswz);
        }
        if (t + 3 < NT) stage_tile(A, brow, K, t + 3, Abuf[(t + 3) & 3], tid);
        __builtin_amdgcn_s_barrier();
        __builtin_amdgcn_s_setprio(1);
        #pragma unroll
        for (int i = 0; i < 4; ++i)
            #pragma unroll
            for (int fn = 0; fn < 4; ++fn)
                acc[i][fn] = __builtin_amdgcn_mfma_f32_16x16x32_f16(
                    af[i], bf[fn], acc[i][fn], 0, 0, 0);
        __builtin_amdgcn_s_setprio(0);
        __builtin_amdgcn_s_barrier();

        // ---- phase 1: A frags (rows 64..127 of wave strip)
        #pragma unroll
        for (int i = 0; i < 4; ++i) {
            int r = wm * 128 + (4 + i) * 16 + lr;
            af[i] = *reinterpret_cast<const f16x8*>((const char*)As + r * 64 + cswz);
        }
        if (t + 3 < NT) stage_tile(W, bcol, K, t + 3, Bbuf[(t + 3) & 3], tid);
        __builtin_amdgcn_s_barrier();
        __builtin_amdgcn_s_setprio(1);
        #pragma unroll
        for (int i = 0; i < 4; ++i)
            #pragma unroll
            for (int fn = 0; fn < 4; ++fn)
                acc[4 + i][fn] = __builtin_amdgcn_mfma_f32_16x16x32_f16(
                    af[i], bf[fn], acc[4 + i][fn], 0, 0, 0);
        __builtin_amdgcn_s_setprio(0);
        // counted gate: allow the (up to) 8 loads of tiles t+2/t+3 to stay in
        // flight; forces tile t+1 complete. Tail tiles tighten the count.
        if (t + 3 < NT)      { asm volatile("s_waitcnt vmcnt(8)" ::: "memory"); }
        else if (t + 2 < NT) { asm volatile("s_waitcnt vmcnt(4)" ::: "memory"); }
        else                 { asm volatile("s_waitcnt vmcnt(0)" ::: "memory"); }
        __builtin_amdgcn_s_barrier();
    }

    // Epilogue: bias + store. C/D frag layout: col = lane&15, row = (lane>>4)*4+j
    #pragma unroll
    for (int fn = 0; fn < 4; ++fn) {
        int col = bcol + wn * 64 + fn * 16 + lr;
        float bv = bias[col];
        #pragma unroll
        for (int fm = 0; fm < 8; ++fm) {
            int row0 = brow + wm * 128 + fm * 16 + (lane >> 4) * 4;
            #pragma unroll
            for (int j = 0; j < 4; ++j) {
                C[(size_t)(row0 + j) * N + col] = (TC)(acc[fm][fn][j] + bv);
            }
        }
    }
}

// ---------------------------------------------------------------- scan
// h_t = tanh(pre_t + h_{t-1} * w), one thread per (b,h) element.
// Parallelism is capped at 1 wave/SIMD (B*H = 64K threads), so the ONLY
// latency hider is the intra-wave load pipeline: PF loads issued per block,
// consumed one block later. Keep the loop body tiny (branchless fast tanh)
// so clang fully unrolls and buf[] stays in VGPRs (rule #20: runtime-indexed
// arrays go to scratch -- that was the round-2 regression, VGPR=40).
__device__ __forceinline__ float fast_tanh(float x) {
    // tanh(x) = 1 - 2/(exp(2x)+1); exp(2x) = exp2(x * 2*log2(e)),
    // branchless, saturates correctly to +/-1 for |x| large.
    float e = __builtin_amdgcn_exp2f(x * 2.8853900817779268f);
    float r = __builtin_amdgcn_rcpf(e + 1.0f);
    return 1.0f - 2.0f * r;
}

template <typename TI, typename TO, int PF>
__global__ __launch_bounds__(256) void scan_kernel(
    const TI* __restrict__ pre, const float* __restrict__ w,
    TO* __restrict__ out) {
    const int S = BB * HH;  // 65536
    const int idx = blockIdx.x * blockDim.x + threadIdx.x;
    const float wv = w[idx & (HH - 1)];
    const TI* p = pre + idx;
    TO* o = out + idx;

    float buf[PF];
    #pragma unroll
    for (int i = 0; i < PF; ++i) buf[i] = (float)p[(size_t)i * S];

    float h = 0.f;
    for (int t0 = 0; t0 < TT; t0 += PF) {
        // 1) issue next block's loads (branchless, clamped; garbage values
        //    beyond T-1 are never consumed)
        float nbuf[PF];
        #pragma unroll
        for (int i = 0; i < PF; ++i) {
            int tp = t0 + PF + i;
            tp = (tp < TT - 1) ? tp : (TT - 1);
            nbuf[i] = (float)p[(size_t)tp * S];
        }
        // 2) serial tanh chain on current block (hides the loads above)
        #pragma unroll
        for (int i = 0; i < PF; ++i) {
            h = fast_tanh(fmaf(h, wv, buf[i]));
            o[(size_t)(t0 + i) * S] = (TO)h;
        }
        // 3) register rename
        #pragma unroll
        for (int i = 0; i < PF; ++i) buf[i] = nbuf[i];
    }
}

__global__ void zero_kernel(float* p, int n) {
    int i = blockIdx.x * blockDim.x + threadIdx.x;
    if (i < n) p[i] = 0.f;
}

// ---------------------------------------------------------------- launch
extern "C" void kernel_launch(void* const* d_in, const int* in_sizes, int n_in,
                              void* d_out, int out_size, void* d_ws, size_t ws_size,
                              hipStream_t stream) {
    const float* x  = (const float*)d_in[0];  // [T,B,D]
    const float* W0 = (const float*)d_in[1];  // [H,D]
    const float* w0 = (const float*)d_in[2];  // [H]
    const float* b0 = (const float*)d_in[3];  // [H]
    const float* W1 = (const float*)d_in[4];  // [H,H]
    const float* w1 = (const float*)d_in[5];  // [H]
    const float* b1 = (const float*)d_in[6];  // [H]
    float* out = (float*)d_out;

    // ws layout:
    //   [0, M*H*2)          : big f16 region (x_f16 first, then out0_f16)
    //   [M*H*2, +H*D*2)     : W0 f16
    //   [.., +H*H*2)        : W1 f16
    //   [.., +M*H*2)        : pre1 f16 (only if ws is big enough)
    const size_t SZ_big = (size_t)MM * HH * sizeof(f16);      // 134 MB
    const size_t O_W0   = SZ_big;
    const size_t O_W1   = O_W0 + (size_t)HH * DD * sizeof(f16);
    const size_t O_pre1 = O_W1 + (size_t)HH * HH * sizeof(f16);
    const bool f16pre1  = (ws_size >= O_pre1 + SZ_big);

    f16* big   = (f16*)d_ws;
    f16* W0h   = (f16*)((char*)d_ws + O_W0);
    f16* W1h   = (f16*)((char*)d_ws + O_W1);
    f16* pre1h = (f16*)((char*)d_ws + O_pre1);

    const int nwg = (MM / 256) * (HH / 256);   // 1024 blocks

    // 1) convert x and weights to f16
    cvt_f32_to_f16<<<(MM * DD) / 8 / 256, 256, 0, stream>>>(x, big, MM * DD);
    cvt_f32_to_f16<<<(HH * DD) / 8 / 256, 256, 0, stream>>>(W0, W0h, HH * DD);
    cvt_f32_to_f16<<<(HH * HH) / 8 / 256, 256, 0, stream>>>(W1, W1h, HH * HH);

    // 2) pre0 = x_f16 @ W0^T + b0 -> d_out reused as f16 scratch
    gemm2<f16><<<nwg, 512, 0, stream>>>(big, W0h, b0, (f16*)d_out, MM, HH, DD);

    // 3) scan layer 0: pre0(f16, d_out) -> out0(f16) into ws big region
    scan_kernel<f16, f16, 32><<<(BB * HH) / 256, 256, 0, stream>>>(
        (const f16*)d_out, w0, big);

    if (f16pre1) {
        // 4) pre1 = out0 @ W1^T + b1 (f16) -> ws
        gemm2<f16><<<nwg, 512, 0, stream>>>(big, W1h, b1, pre1h, MM, HH, HH);
        // 5) scan layer 1: pre1(f16, ws) -> out (f32)
        scan_kernel<f16, float, 32><<<(BB * HH) / 256, 256, 0, stream>>>(
            pre1h, w1, out);
    } else {
        // 4) pre1 (f32) -> d_out, then in-place scan
        gemm2<float><<<nwg, 512, 0, stream>>>(big, W1h, b1, out, MM, HH, HH);
        scan_kernel<float, float, 32><<<(BB * HH) / 256, 256, 0, stream>>>(
            out, w1, out);
    }

    // 6) hidden output: zeros [2,B,H] appended after [T,B,H]
    zero_kernel<<<(2 * BB * HH) / 256, 256, 0, stream>>>(
        out + (size_t)MM * HH, 2 * BB * HH);
}

// Round 5
// 435.420 us; speedup vs baseline: 2.6917x; 1.1474x over previous
//
#include <hip/hip_runtime.h>
#include <hip/hip_fp16.h>
#include <cstdint>
#include <cstddef>

// Problem dims (fixed by the reference)
#define TT 1024
#define BB 64
#define DD 512
#define HH 1024
#define MM (TT * BB)   // 65536 rows for the batched GEMM

typedef _Float16 f16;
typedef _Float16 f16x8 __attribute__((ext_vector_type(8)));
typedef float f32x4 __attribute__((ext_vector_type(4)));

// ---------------------------------------------------------------- converts
__global__ void cvt_f32_to_f16(const float* __restrict__ src,
                               f16* __restrict__ dst, int n) {
    int i = blockIdx.x * blockDim.x + threadIdx.x;
    int idx = i * 8;
    if (idx + 8 <= n) {
        float4 a = *reinterpret_cast<const float4*>(src + idx);
        float4 b = *reinterpret_cast<const float4*>(src + idx + 4);
        f16x8 o;
        o[0] = (f16)a.x; o[1] = (f16)a.y; o[2] = (f16)a.z; o[3] = (f16)a.w;
        o[4] = (f16)b.x; o[5] = (f16)b.y; o[6] = (f16)b.z; o[7] = (f16)b.w;
        *reinterpret_cast<f16x8*>(dst + idx) = o;
    } else {
        for (int k = idx; k < n; ++k) dst[k] = (f16)src[k];
    }
}

// ---------------------------------------------------------------- GEMM
// C[M,N] = A[M,K] (f16 row-major) * W[N,K]^T (f16 row-major) + bias[N]
// 256x256 tile, BK=64, 8 waves (2M x 4N), double-buffered 128-KiB LDS,
// 4 phases per K-tile (<=12 ds_read_b128 -> barrier -> lgkmcnt(0) ->
// setprio+16 MFMA -> barrier), B-frag register reuse, staging split 4+4
// into phases 2/3, one vmcnt(8) gate per K-tile (never 0 mid-loop),
// (row&7)<<4 XOR swizzle on 128-B LDS rows (conflict-free ds_read_b128).
__device__ __forceinline__ void gload16(const void* g, void* l) {
    __builtin_amdgcn_global_load_lds(
        (const __attribute__((address_space(1))) void*)g,
        (__attribute__((address_space(3))) void*)l, 16, 0, 0);
}

// Stage one 256x64 f16 K-tile (32 KiB): 512 threads x 4 x 16B.
// LDS dest lane-linear (gload_lds requirement); swizzle applied by
// inverse-permuting the GLOBAL source address (m173 pattern).
__device__ __forceinline__ void stage64(const f16* __restrict__ G,
                                        int rowbase, int K, int kt,
                                        f16* lbuf, int tid) {
    #pragma unroll
    for (int j = 0; j < 4; ++j) {
        int p   = (j * 512 + tid) * 16;        // physical byte in tile
        int row = p >> 7;                      // 0..255 (128-B rows)
        int lc  = (p & 127) ^ ((row & 7) << 4);// logical col byte
        gload16(G + (size_t)(rowbase + row) * K + kt * 64 + (lc >> 1),
                (char*)lbuf + p);
    }
}

// Read an MFMA A/B fragment: tile-local row r (r&7 == lr&7 by construction),
// k-subtile s (0/1). Physical col 16B-chunk = (s*4 + kg) ^ (lr&7).
__device__ __forceinline__ f16x8 ldfrag(const f16* buf, int r, int s,
                                        int kg, int lr) {
    int c = ((s * 4 + kg) ^ (lr & 7)) << 4;
    return *reinterpret_cast<const f16x8*>((const char*)buf + r * 128 + c);
}

template <typename TC>
__global__ __launch_bounds__(512, 2) void gemm3(
    const f16* __restrict__ A, const f16* __restrict__ W,
    const float* __restrict__ bias, TC* __restrict__ C,
    int M, int N, int K) {
    // [matrix][dbuf][256*64]; contiguous 128 KiB (reused as C-tile in epilogue)
    __shared__ f16 lds[2][2][256 * 64];

    const int tid  = threadIdx.x;
    const int lane = tid & 63;
    const int wid  = tid >> 6;      // 0..7
    const int wm   = wid >> 2;      // 0..1 -> 128-row strip
    const int wn   = wid & 3;       // 0..3 -> 64-col strip
    const int lr   = lane & 15;
    const int kg   = lane >> 4;     // 0..3

    // XCD-bijective block swizzle (nwg % 8 == 0 here), col-fastest chunks
    const int nwg = gridDim.x;
    int bid = blockIdx.x;
    int wg  = (nwg % 8 == 0) ? ((bid & 7) * (nwg >> 3) + (bid >> 3)) : bid;
    const int ncol = N >> 8;
    const int brow = (wg / ncol) << 8;
    const int bcol = (wg % ncol) << 8;

    const int NT = K >> 6;          // K-tiles of 64 (>= 8 here)

    f32x4 acc[8][4] = {};
    f16x8 aA[4][2], b0[2][2], b1[2][2];

    // Prologue: stage tiles 0 and 1; vmcnt(8) leaves tile-1's 8 in flight.
    stage64(A, brow, K, 0, lds[0][0], tid);
    stage64(W, bcol, K, 0, lds[1][0], tid);
    stage64(A, brow, K, 1, lds[0][1], tid);
    stage64(W, bcol, K, 1, lds[1][1], tid);
    asm volatile("s_waitcnt vmcnt(8)" ::: "memory");
    __builtin_amdgcn_s_barrier();

    for (int t = 0; t < NT; ++t) {
        const f16* As = lds[0][t & 1];
        const f16* Bs = lds[1][t & 1];
        const bool st = (t + 2 < NT);

        // ---- phase 0: quadrant (mh0, nh0); read A[mh0] (8) + B0 (4)
        #pragma unroll
        for (int i = 0; i < 4; ++i)
            #pragma unroll
            for (int s = 0; s < 2; ++s)
                aA[i][s] = ldfrag(As, wm * 128 + i * 16 + lr, s, kg, lr);
        #pragma unroll
        for (int n = 0; n < 2; ++n)
            #pragma unroll
            for (int s = 0; s < 2; ++s)
                b0[n][s] = ldfrag(Bs, wn * 64 + n * 16 + lr, s, kg, lr);
        __builtin_amdgcn_s_barrier();
        asm volatile("s_waitcnt lgkmcnt(0)" ::: "memory");
        __builtin_amdgcn_s_setprio(1);
        #pragma unroll
        for (int i = 0; i < 4; ++i)
            #pragma unroll
            for (int n = 0; n < 2; ++n)
                #pragma unroll
                for (int s = 0; s < 2; ++s)
                    acc[i][n] = __builtin_amdgcn_mfma_f32_16x16x32_f16(
                        aA[i][s], b0[n][s], acc[i][n], 0, 0, 0);
        __builtin_amdgcn_s_setprio(0);
        __builtin_amdgcn_s_barrier();

        // ---- phase 1: (mh0, nh1); read B1 (4)
        #pragma unroll
        for (int n = 0; n < 2; ++n)
            #pragma unroll
            for (int s = 0; s < 2; ++s)
                b1[n][s] = ldfrag(Bs, wn * 64 + (2 + n) * 16 + lr, s, kg, lr);
        __builtin_amdgcn_s_barrier();
        asm volatile("s_waitcnt lgkmcnt(0)" ::: "memory");
        __builtin_amdgcn_s_setprio(1);
        #pragma unroll
        for (int i = 0; i < 4; ++i)
            #pragma unroll
            for (int n = 0; n < 2; ++n)
                #pragma unroll
                for (int s = 0; s < 2; ++s)
                    acc[i][2 + n] = __builtin_amdgcn_mfma_f32_16x16x32_f16(
                        aA[i][s], b1[n][s], acc[i][2 + n], 0, 0, 0);
        __builtin_amdgcn_s_setprio(0);
        __builtin_amdgcn_s_barrier();

        // ---- phase 2: (mh1, nh0); read A[mh1] (8, overwrite aA); stage B(t+2)
        #pragma unroll
        for (int i = 0; i < 4; ++i)
            #pragma unroll
            for (int s = 0; s < 2; ++s)
                aA[i][s] = ldfrag(As, wm * 128 + (4 + i) * 16 + lr, s, kg, lr);
        if (st) stage64(W, bcol, K, t + 2, lds[1][t & 1], tid);
        __builtin_amdgcn_s_barrier();
        asm volatile("s_waitcnt lgkmcnt(0)" ::: "memory");
        __builtin_amdgcn_s_setprio(1);
        #pragma unroll
        for (int i = 0; i < 4; ++i)
            #pragma unroll
            for (int n = 0; n < 2; ++n)
                #pragma unroll
                for (int s = 0; s < 2; ++s)
                    acc[4 + i][n] = __builtin_amdgcn_mfma_f32_16x16x32_f16(
                        aA[i][s], b0[n][s], acc[4 + i][n], 0, 0, 0);
        __builtin_amdgcn_s_setprio(0);
        __builtin_amdgcn_s_barrier();

        // ---- phase 3: (mh1, nh1); no reads; stage A(t+2); gate per K-tile
        if (st) stage64(A, brow, K, t + 2, lds[0][t & 1], tid);
        __builtin_amdgcn_s_barrier();
        __builtin_amdgcn_s_setprio(1);
        #pragma unroll
        for (int i = 0; i < 4; ++i)
            #pragma unroll
            for (int n = 0; n < 2; ++n)
                #pragma unroll
                for (int s = 0; s < 2; ++s)
                    acc[4 + i][2 + n] = __builtin_amdgcn_mfma_f32_16x16x32_f16(
                        aA[i][s], b1[n][s], acc[4 + i][2 + n], 0, 0, 0);
        __builtin_amdgcn_s_setprio(0);
        if (st)                { asm volatile("s_waitcnt vmcnt(8)" ::: "memory"); }
        else if (t + 1 < NT)   { asm volatile("s_waitcnt vmcnt(0)" ::: "memory"); }
        __builtin_amdgcn_s_barrier();
    }

    if constexpr (sizeof(TC) == 2) {
        // Epilogue via LDS repack: 128 KiB = [256][256] f16 C-tile,
        // 512-B rows, (row&7)<<4 XOR swizzle; then coalesced 16-B stores.
        f16* Ct = &lds[0][0][0];
        #pragma unroll
        for (int fn = 0; fn < 4; ++fn) {
            int col = wn * 64 + fn * 16 + lr;
            float bv = bias[bcol + col];
            #pragma unroll
            for (int fm = 0; fm < 8; ++fm) {
                int row0 = wm * 128 + fm * 16 + kg * 4;
                #pragma unroll
                for (int j = 0; j < 4; ++j) {
                    int r  = row0 + j;
                    int pb = r * 512 + ((col * 2) ^ ((r & 7) << 4));
                    *(f16*)((char*)Ct + pb) = (f16)(acc[fm][fn][j] + bv);
                }
            }
        }
        __builtin_amdgcn_s_barrier();
        asm volatile("s_waitcnt lgkmcnt(0)" ::: "memory");
        #pragma unroll
        for (int i = 0; i < 16; ++i) {
            int e   = (i * 512 + tid) * 16;     // byte in [256][512B]
            int row = e >> 9;
            int cb  = e & 511;
            int pb  = row * 512 + (cb ^ ((row & 7) << 4));
            f16x8 v = *(const f16x8*)((const char*)Ct + pb);
            *reinterpret_cast<f16x8*>(
                (f16*)C + (size_t)(brow + row) * N + bcol + (cb >> 1)) = v;
        }
    } else {
        // f32 fallback: scattered stores (tile doesn't fit LDS)
        #pragma unroll
        for (int fn = 0; fn < 4; ++fn) {
            int col = bcol + wn * 64 + fn * 16 + lr;
            float bv = bias[col];
            #pragma unroll
            for (int fm = 0; fm < 8; ++fm) {
                int row0 = brow + wm * 128 + fm * 16 + kg * 4;
                #pragma unroll
                for (int j = 0; j < 4; ++j)
                    C[(size_t)(row0 + j) * N + col] = (TC)(acc[fm][fn][j] + bv);
            }
        }
    }
}

// ---------------------------------------------------------------- scan
// h_t = tanh(pre_t + h_{t-1} * w), one thread per (b,h) element.
// PF-deep branchless load pipeline; tiny body so clang fully unrolls and
// buf[] stays in VGPRs (rule #20).
__device__ __forceinline__ float fast_tanh(float x) {
    float e = __builtin_amdgcn_exp2f(x * 2.8853900817779268f);  // exp(2x)
    float r = __builtin_amdgcn_rcpf(e + 1.0f);
    return 1.0f - 2.0f * r;
}

template <typename TI, typename TO, int PF>
__global__ __launch_bounds__(256) void scan_kernel(
    const TI* __restrict__ pre, const float* __restrict__ w,
    TO* __restrict__ out) {
    const int S = BB * HH;  // 65536
    const int idx = blockIdx.x * blockDim.x + threadIdx.x;
    const float wv = w[idx & (HH - 1)];
    const TI* p = pre + idx;
    TO* o = out + idx;

    float buf[PF];
    #pragma unroll
    for (int i = 0; i < PF; ++i) buf[i] = (float)p[(size_t)i * S];

    float h = 0.f;
    for (int t0 = 0; t0 < TT; t0 += PF) {
        float nbuf[PF];
        #pragma unroll
        for (int i = 0; i < PF; ++i) {
            int tp = t0 + PF + i;
            tp = (tp < TT - 1) ? tp : (TT - 1);
            nbuf[i] = (float)p[(size_t)tp * S];
        }
        #pragma unroll
        for (int i = 0; i < PF; ++i) {
            h = fast_tanh(fmaf(h, wv, buf[i]));
            o[(size_t)(t0 + i) * S] = (TO)h;
        }
        #pragma unroll
        for (int i = 0; i < PF; ++i) buf[i] = nbuf[i];
    }
}

__global__ void zero_kernel(float* p, int n) {
    int i = blockIdx.x * blockDim.x + threadIdx.x;
    if (i < n) p[i] = 0.f;
}

// ---------------------------------------------------------------- launch
extern "C" void kernel_launch(void* const* d_in, const int* in_sizes, int n_in,
                              void* d_out, int out_size, void* d_ws, size_t ws_size,
                              hipStream_t stream) {
    const float* x  = (const float*)d_in[0];  // [T,B,D]
    const float* W0 = (const float*)d_in[1];  // [H,D]
    const float* w0 = (const float*)d_in[2];  // [H]
    const float* b0 = (const float*)d_in[3];  // [H]
    const float* W1 = (const float*)d_in[4];  // [H,H]
    const float* w1 = (const float*)d_in[5];  // [H]
    const float* b1 = (const float*)d_in[6];  // [H]
    float* out = (float*)d_out;

    const size_t SZ_big = (size_t)MM * HH * sizeof(f16);      // 134 MB
    const size_t O_W0   = SZ_big;
    const size_t O_W1   = O_W0 + (size_t)HH * DD * sizeof(f16);
    const size_t O_pre1 = O_W1 + (size_t)HH * HH * sizeof(f16);
    const bool f16pre1  = (ws_size >= O_pre1 + SZ_big);

    f16* big   = (f16*)d_ws;
    f16* W0h   = (f16*)((char*)d_ws + O_W0);
    f16* W1h   = (f16*)((char*)d_ws + O_W1);
    f16* pre1h = (f16*)((char*)d_ws + O_pre1);

    const int nwg = (MM / 256) * (HH / 256);   // 1024 blocks

    // 1) convert x and weights to f16
    cvt_f32_to_f16<<<(MM * DD) / 8 / 256, 256, 0, stream>>>(x, big, MM * DD);
    cvt_f32_to_f16<<<(HH * DD) / 8 / 256, 256, 0, stream>>>(W0, W0h, HH * DD);
    cvt_f32_to_f16<<<(HH * HH) / 8 / 256, 256, 0, stream>>>(W1, W1h, HH * HH);

    // 2) pre0 = x_f16 @ W0^T + b0 -> d_out reused as f16 scratch
    gemm3<f16><<<nwg, 512, 0, stream>>>(big, W0h, b0, (f16*)d_out, MM, HH, DD);

    // 3) scan layer 0: pre0(f16, d_out) -> out0(f16) into ws big region
    scan_kernel<f16, f16, 32><<<(BB * HH) / 256, 256, 0, stream>>>(
        (const f16*)d_out, w0, big);

    if (f16pre1) {
        // 4) pre1 = out0 @ W1^T + b1 (f16) -> ws
        gemm3<f16><<<nwg, 512, 0, stream>>>(big, W1h, b1, pre1h, MM, HH, HH);
        // 5) scan layer 1: pre1(f16, ws) -> out (f32)
        scan_kernel<f16, float, 32><<<(BB * HH) / 256, 256, 0, stream>>>(
            pre1h, w1, out);
    } else {
        // 4) pre1 (f32) -> d_out, then in-place scan
        gemm3<float><<<nwg, 512, 0, stream>>>(big, W1h, b1, out, MM, HH, HH);
        scan_kernel<float, float, 32><<<(BB * HH) / 256, 256, 0, stream>>>(
            out, w1, out);
    }

    // 6) hidden output: zeros [2,B,H] appended after [T,B,H]
    zero_kernel<<<(2 * BB * HH) / 256, 256, 0, stream>>>(
        out + (size_t)MM * HH, 2 * BB * HH);
}